// Round 1
// baseline (1488.428 us; speedup 1.0000x reference)
//
#include <hip/hip_runtime.h>
#include <math.h>

// MoE fused kernel: gating MLP (2->64->64->64->16, tanh, sin(5*pi*logits))
// + 16 experts (2->128->128->128->128->1, tanh) + gate-weighted sum.
// All fp32, fully fused: h ping-pongs in LDS, weights via lane-uniform
// scalar loads (s_load), zero intermediate HBM traffic.

#define TOK_PER_BLK 64
#define THREADS 512          // 8 wave-uniform j-groups x 64 tokens
#define N_TOK 65536
#define SMEM_FLOATS (8192 + 8192 + 1024 + 512)   // hA, hB, gates, part
#define SMEM_BYTES (SMEM_FLOATS * 4)             // 71680 B -> 2 blocks/CU

__device__ __forceinline__ float tanh_fast(float x) {
    // tanh(x) = 1 - 2/(exp(2x)+1); safe at +/-inf (exp->0 or inf).
    float e = __expf(2.0f * x);
    return 1.0f - 2.0f / (e + 1.0f);
}

__launch_bounds__(THREADS, 4)
__global__ void moe_fused(const float* __restrict__ x,
                          const float* __restrict__ ew1,
                          const float* __restrict__ eb1,
                          const float* __restrict__ ewm,
                          const float* __restrict__ ebm,
                          const float* __restrict__ ewo,
                          const float* __restrict__ ebo,
                          const float* __restrict__ gw1,
                          const float* __restrict__ gb1,
                          const float* __restrict__ gwm,
                          const float* __restrict__ gbm,
                          const float* __restrict__ gwo,
                          const float* __restrict__ gbo,
                          float* __restrict__ y) {
    extern __shared__ float smem[];
    float* hA   = smem;          // [128][64]
    float* hB   = smem + 8192;   // [128][64]
    float* gts  = smem + 16384;  // [16][64]  gates, survive expert loop
    float* part = smem + 17408;  // [8][64]   output-dot partials

    const int i = threadIdx.x & 63;                                   // token lane
    const int p = __builtin_amdgcn_readfirstlane(threadIdx.x >> 6);   // wave-uniform group
    const int tok = blockIdx.x * TOK_PER_BLK + i;

    const float x0 = x[tok * 2 + 0];
    const float x1 = x[tok * 2 + 1];

    // ---------------- gating: 2 -> 64 -> 64 -> 64 -> 16 ----------------
    {   // L1: each p-group writes 8 rows of g into hA
        const int j0 = p * 8;
        #pragma unroll
        for (int m = 0; m < 8; ++m) {
            const int j = j0 + m;
            float pre = fmaf(x0, gw1[j], fmaf(x1, gw1[64 + j], gb1[j]));
            hA[j * 64 + i] = tanh_fast(pre);
        }
    }
    __syncthreads();

    #pragma unroll 1
    for (int l = 0; l < 2; ++l) {   // two 64x64 tanh layers, ping-pong
        const float* gin  = (l & 1) ? hB : hA;
        float*       gout = (l & 1) ? hA : hB;
        const float* w = gwm + l * 64 * 64;
        const int j0 = p * 8;
        float acc[8];
        #pragma unroll
        for (int m = 0; m < 8; ++m) acc[m] = gbm[l * 64 + j0 + m];
        #pragma unroll 1
        for (int k = 0; k < 64; k += 4) {
            float g0 = gin[(k + 0) * 64 + i];
            float g1 = gin[(k + 1) * 64 + i];
            float g2 = gin[(k + 2) * 64 + i];
            float g3 = gin[(k + 3) * 64 + i];
            const float* w0 = w + (k + 0) * 64 + j0;
            const float* w1 = w + (k + 1) * 64 + j0;
            const float* w2 = w + (k + 2) * 64 + j0;
            const float* w3 = w + (k + 3) * 64 + j0;
            #pragma unroll
            for (int m = 0; m < 8; ++m) acc[m] = fmaf(g0, w0[m], acc[m]);
            #pragma unroll
            for (int m = 0; m < 8; ++m) acc[m] = fmaf(g1, w1[m], acc[m]);
            #pragma unroll
            for (int m = 0; m < 8; ++m) acc[m] = fmaf(g2, w2[m], acc[m]);
            #pragma unroll
            for (int m = 0; m < 8; ++m) acc[m] = fmaf(g3, w3[m], acc[m]);
        }
        #pragma unroll
        for (int m = 0; m < 8; ++m) gout[(j0 + m) * 64 + i] = tanh_fast(acc[m]);
        __syncthreads();
    }
    // after l=0: g in hB; after l=1: g in hA.
    {   // logits + gates: each p-group computes experts e=2p, 2p+1 (full 64-k dot)
        const int e0 = p * 2;
        float l0 = gbo[e0 + 0];
        float l1 = gbo[e0 + 1];
        #pragma unroll 1
        for (int k = 0; k < 64; k += 2) {
            float ga = hA[(k + 0) * 64 + i];
            float gb = hA[(k + 1) * 64 + i];
            l0 = fmaf(ga, gwo[(k + 0) * 16 + e0 + 0], l0);
            l1 = fmaf(ga, gwo[(k + 0) * 16 + e0 + 1], l1);
            l0 = fmaf(gb, gwo[(k + 1) * 16 + e0 + 0], l0);
            l1 = fmaf(gb, gwo[(k + 1) * 16 + e0 + 1], l1);
        }
        const float FIVE_PI = 15.707963267948966f;
        gts[(e0 + 0) * 64 + i] = sinf(FIVE_PI * l0);
        gts[(e0 + 1) * 64 + i] = sinf(FIVE_PI * l1);
    }
    __syncthreads();

    // ---------------- experts: 2 -> 128 -> (128 -> 128 -> 128) -> 1 ----------------
    float yacc = 0.0f;
    const int j0 = p * 16;
    #pragma unroll 1
    for (int e = 0; e < 16; ++e) {
        const float* w1 = ew1 + e * 2 * 128;
        const float* b1 = eb1 + e * 128;
        const float* wm = ewm + e * 3 * 128 * 128;
        const float* bm = ebm + e * 3 * 128;
        const float* wo = ewo + e * 128;

        // EL1: x -> hA
        #pragma unroll
        for (int m = 0; m < 16; ++m) {
            const int j = j0 + m;
            float pre = fmaf(x0, w1[j], fmaf(x1, w1[128 + j], b1[j]));
            hA[j * 64 + i] = tanh_fast(pre);
        }
        __syncthreads();

        // EL2..EL4: three 128x128 tanh layers, ping-pong hA/hB
        #pragma unroll 1
        for (int l = 0; l < 3; ++l) {
            const float* hin  = (l & 1) ? hB : hA;
            float*       hout = (l & 1) ? hA : hB;
            const float* w = wm + l * 128 * 128;
            float acc[16];
            #pragma unroll
            for (int m = 0; m < 16; ++m) acc[m] = bm[l * 128 + j0 + m];
            #pragma unroll 1
            for (int k = 0; k < 128; k += 4) {
                float h0 = hin[(k + 0) * 64 + i];
                float h1 = hin[(k + 1) * 64 + i];
                float h2 = hin[(k + 2) * 64 + i];
                float h3 = hin[(k + 3) * 64 + i];
                const float* w0 = w + (k + 0) * 128 + j0;
                const float* w1r = w + (k + 1) * 128 + j0;
                const float* w2r = w + (k + 2) * 128 + j0;
                const float* w3r = w + (k + 3) * 128 + j0;
                #pragma unroll
                for (int m = 0; m < 16; ++m) acc[m] = fmaf(h0, w0[m], acc[m]);
                #pragma unroll
                for (int m = 0; m < 16; ++m) acc[m] = fmaf(h1, w1r[m], acc[m]);
                #pragma unroll
                for (int m = 0; m < 16; ++m) acc[m] = fmaf(h2, w2r[m], acc[m]);
                #pragma unroll
                for (int m = 0; m < 16; ++m) acc[m] = fmaf(h3, w3r[m], acc[m]);
            }
            #pragma unroll
            for (int m = 0; m < 16; ++m) hout[(j0 + m) * 64 + i] = tanh_fast(acc[m]);
            __syncthreads();
        }
        // final h is in hB (l=2 wrote hB)

        // ELout: per-group partial of the 128-dot with ewo
        {
            float ps = 0.0f;
            #pragma unroll
            for (int m = 0; m < 16; ++m) {
                const int k = p * 16 + m;
                ps = fmaf(hB[k * 64 + i], wo[k], ps);
            }
            part[p * 64 + i] = ps;
        }
        __syncthreads();
        if (p == 0) {   // wave 0: reduce 8 partials, apply gate, accumulate y
            float eo = ebo[e];
            #pragma unroll
            for (int q = 0; q < 8; ++q) eo += part[q * 64 + i];
            yacc = fmaf(gts[e * 64 + i], eo, yacc);
        }
        // no barrier needed here: next write of `part` is 4 barriers away,
        // next write of hA (EL1 of e+1) conflicts with nothing p0 reads.
    }

    if (p == 0) y[tok] = yacc;
}

extern "C" void kernel_launch(void* const* d_in, const int* in_sizes, int n_in,
                              void* d_out, int out_size, void* d_ws, size_t ws_size,
                              hipStream_t stream) {
    const float* x   = (const float*)d_in[0];
    const float* ew1 = (const float*)d_in[1];
    const float* eb1 = (const float*)d_in[2];
    const float* ewm = (const float*)d_in[3];
    const float* ebm = (const float*)d_in[4];
    const float* ewo = (const float*)d_in[5];
    const float* ebo = (const float*)d_in[6];
    const float* gw1 = (const float*)d_in[7];
    const float* gb1 = (const float*)d_in[8];
    const float* gwm = (const float*)d_in[9];
    const float* gbm = (const float*)d_in[10];
    const float* gwo = (const float*)d_in[11];
    const float* gbo = (const float*)d_in[12];
    float* y = (float*)d_out;

    // 70 KB dynamic LDS per block (> 64 KB default) -> raise the cap.
    hipFuncSetAttribute((const void*)moe_fused,
                        hipFuncAttributeMaxDynamicSharedMemorySize, SMEM_BYTES);

    dim3 grid(N_TOK / TOK_PER_BLK);   // 1024 blocks
    dim3 block(THREADS);              // 512 threads = 8 waves
    moe_fused<<<grid, block, SMEM_BYTES, stream>>>(
        x, ew1, eb1, ewm, ebm, ewo, ebo, gw1, gb1, gwm, gbm, gwo, gbo, y);
}

// Round 2
// 549.933 us; speedup vs baseline: 2.7066x; 2.7066x over previous
//
#include <hip/hip_runtime.h>
#include <math.h>

// Fused MoE: gating MLP in fp32 VALU + 16 experts on MFMA (bf16 2-term split
// activations x bf16-RNE weights), gate-weighted sum. T=128 tokens/block,
// 8 waves x 16-token disjoint slices, h packed (hi|lo) u32 in swizzled LDS.

#define N_TOK 65536
#define T_BLK 128
#define THREADS 512
// LDS: h 64KB | Wstage 2x32KB | gates 8KB
#define SMEM_BYTES (65536 + 65536 + 8192)

typedef short bf16x8 __attribute__((ext_vector_type(8)));
typedef float f32x4  __attribute__((ext_vector_type(4)));

__device__ __forceinline__ float tanh_fast(float x) {
    float e = __expf(2.0f * x);                       // v_mul + v_exp
    return fmaf(-2.0f, __builtin_amdgcn_rcpf(e + 1.0f), 1.0f);
}

// pack fp32 -> (bf16_hi | bf16_lo) in one u32 (hi truncated, lo = remainder)
__device__ __forceinline__ unsigned pack_hl(float v) {
    unsigned u  = __float_as_uint(v);
    unsigned hi = u & 0xffff0000u;
    float    r  = v - __uint_as_float(hi);
    unsigned lo = __float_as_uint(r) >> 16;
    return hi | lo;
}

__device__ __forceinline__ void stage16(const void* g, void* l) {
    __builtin_amdgcn_global_load_lds(
        (const __attribute__((address_space(1))) void*)g,
        (__attribute__((address_space(3))) void*)l, 16, 0, 0);
}

// ---------------- prep: pack ewm -> bf16 A-fragments (W^T) in ws ----------------
// layout: [el=e*3+l][ (mt*4+ks)*64 + lane ] * 16B ; frag elem u: j=mt*16+(lane&15),
// k = ks*32 + (lane>>4)*8 + u ; value = W[k][j] = ewm[el][k][j]
__launch_bounds__(256)
__global__ void pack_wm_kernel(const float* __restrict__ ewm,
                               unsigned short* __restrict__ wsA) {
    int t    = blockIdx.x * 256 + threadIdx.x;   // 48*8*4*64 = 98304
    int lane = t & 63;
    int ks   = (t >> 6) & 3;
    int mt   = (t >> 8) & 7;
    int el   = t >> 11;                          // 0..47
    int j    = mt * 16 + (lane & 15);
    int k0   = ks * 32 + (lane >> 4) * 8;
    const float* src = ewm + (size_t)el * 16384;
    unsigned short o[8];
#pragma unroll
    for (int u = 0; u < 8; ++u) {
        unsigned b = __float_as_uint(src[(k0 + u) * 128 + j]);
        b += 0x7fffu + ((b >> 16) & 1u);         // RNE to bf16
        o[u] = (unsigned short)(b >> 16);
    }
    uint4 v;
    v.x = (unsigned)o[0] | ((unsigned)o[1] << 16);
    v.y = (unsigned)o[2] | ((unsigned)o[3] << 16);
    v.z = (unsigned)o[4] | ((unsigned)o[5] << 16);
    v.w = (unsigned)o[6] | ((unsigned)o[7] << 16);
    *(uint4*)(wsA + (size_t)el * 16384 + (size_t)((mt * 4 + ks) * 64 + lane) * 8) = v;
}

// ---------------- main fused kernel ----------------
__launch_bounds__(THREADS, 2)
__global__ void moe_fused(const float* __restrict__ x,
                          const float* __restrict__ ew1,
                          const float* __restrict__ eb1,
                          const float* __restrict__ ewm,   // unused (prepacked) but kept
                          const float* __restrict__ ebm,
                          const float* __restrict__ ewo,
                          const float* __restrict__ ebo,
                          const float* __restrict__ gw1,
                          const float* __restrict__ gb1,
                          const float* __restrict__ gwm,
                          const float* __restrict__ gbm,
                          const float* __restrict__ gwo,
                          const float* __restrict__ gbo,
                          const unsigned short* __restrict__ wsA,
                          float* __restrict__ y) {
    extern __shared__ char smem[];
    unsigned* hbuf    = (unsigned*)smem;            // [128 tok][128 u32] swizzled
    char*     wbuf    = smem + 65536;               // 2 x 32KB W fragments
    float*    gates_l = (float*)(smem + 131072);    // [16][128]

    const int tid = threadIdx.x;
    const int blk = blockIdx.x;
    const char* wsA_b = (const char*)wsA;

    // swizzled 16B-unit pointer into h
    auto hp = [&](int tok, int unit) -> uint4* {
        return (uint4*)(hbuf + tok * 128 + ((unit ^ (tok & 7)) << 2));
    };

    // ---- issue stage of W(e0,l0) into buf0 (overlaps gating) ----
    {
#pragma unroll
        for (int r = 0; r < 4; ++r)
            stage16(wsA_b + (size_t)((r * 512 + tid) << 4),
                    wbuf + ((r * 512 + tid) << 4));
    }

    // ================= gating (fp32 VALU) =================
    {
        const int tk = tid & 127;
        const int q  = tid >> 7;                    // wave-uniform (0..3)
        const int j0 = q * 16;
        float* gA = (float*)smem;                   // [64][128]
        float* gB = gA + 8192;
        const float gx0 = x[(blk * T_BLK + tk) * 2 + 0];
        const float gx1 = x[(blk * T_BLK + tk) * 2 + 1];
#pragma unroll
        for (int m = 0; m < 16; ++m) {
            int j = j0 + m;
            float pre = fmaf(gx0, gw1[j], fmaf(gx1, gw1[64 + j], gb1[j]));
            gA[j * 128 + tk] = tanh_fast(pre);
        }
        __syncthreads();
#pragma unroll 1
        for (int l = 0; l < 2; ++l) {
            const float* gin  = l ? gB : gA;
            float*       gout = l ? gA : gB;
            const float* w  = gwm + l * 4096;
            const float* bb = gbm + l * 64;
            float acc[16];
#pragma unroll
            for (int m = 0; m < 16; ++m) acc[m] = bb[j0 + m];
#pragma unroll 4
            for (int k = 0; k < 64; ++k) {
                float gv = gin[k * 128 + tk];
                const float* wr = w + k * 64 + j0;
#pragma unroll
                for (int m = 0; m < 16; ++m) acc[m] = fmaf(gv, wr[m], acc[m]);
            }
#pragma unroll
            for (int m = 0; m < 16; ++m) gout[(j0 + m) * 128 + tk] = tanh_fast(acc[m]);
            __syncthreads();
        }
        // logits: q-group computes experts q*4..q*4+3 ; g is in gA
        float lg[4];
#pragma unroll
        for (int m = 0; m < 4; ++m) lg[m] = gbo[q * 4 + m];
#pragma unroll 4
        for (int k = 0; k < 64; ++k) {
            float gv = gA[k * 128 + tk];
            const float* wr = gwo + k * 16 + q * 4;
#pragma unroll
            for (int m = 0; m < 4; ++m) lg[m] = fmaf(gv, wr[m], lg[m]);
        }
        const float FIVE_PI = 15.707963267948966f;
#pragma unroll
        for (int m = 0; m < 4; ++m)
            gates_l[(q * 4 + m) * 128 + tk] = __sinf(FIVE_PI * lg[m]);
        __syncthreads();   // gates + gA reads done before experts clobber hbuf
    }

    // ================= experts (MFMA) =================
    const int lane = tid & 63;
    const int w_id = tid >> 6;       // 0..7
    const int lrow = lane & 15;
    const int g4   = lane >> 4;      // 0..3
    const int tok  = w_id * 16 + lrow;   // this wave's token slice (disjoint)
    const float ex0 = x[(blk * T_BLK + tok) * 2 + 0];
    const float ex1 = x[(blk * T_BLK + tok) * 2 + 1];
    float yacc = 0.0f;

#pragma unroll 1
    for (int e = 0; e < 16; ++e) {
        // ---- EL1: 2 -> 128 (intra-wave rows only, no barrier) ----
        {
            const float* w1 = ew1 + e * 256;
            const float* b1 = eb1 + e * 128;
#pragma unroll
            for (int c = 0; c < 8; ++c) {
                int j = g4 * 32 + c * 4;
                const float4 wa = *(const float4*)(w1 + j);
                const float4 wb = *(const float4*)(w1 + 128 + j);
                const float4 bb = *(const float4*)(b1 + j);
                uint4 pk;
                pk.x = pack_hl(tanh_fast(fmaf(ex0, wa.x, fmaf(ex1, wb.x, bb.x))));
                pk.y = pack_hl(tanh_fast(fmaf(ex0, wa.y, fmaf(ex1, wb.y, bb.y))));
                pk.z = pack_hl(tanh_fast(fmaf(ex0, wa.z, fmaf(ex1, wb.z, bb.z))));
                pk.w = pack_hl(tanh_fast(fmaf(ex0, wa.w, fmaf(ex1, wb.w, bb.w))));
                *hp(tok, g4 * 8 + c) = pk;
            }
        }
        // ---- 3 mid layers, MFMA ----
#pragma unroll 1
        for (int l = 0; l < 3; ++l) {
            const int s = e * 3 + l;
            __syncthreads();                       // stage(s) complete; buf free
            if (s + 1 < 48) {                      // prefetch next W
                const char* gsrc = wsA_b + (size_t)(s + 1) * 32768;
                char* ldst = wbuf + ((s + 1) & 1) * 32768;
#pragma unroll
                for (int r = 0; r < 4; ++r)
                    stage16(gsrc + ((r * 512 + tid) << 4),
                            ldst + ((r * 512 + tid) << 4));
            }
            const char* wc = wbuf + (s & 1) * 32768;

            // B fragments: this wave's own 16 token rows (hi/lo split)
            bf16x8 Bhi[4], Blo[4];
#pragma unroll
            for (int ks = 0; ks < 4; ++ks) {
                int u0 = ks * 8 + g4 * 2;
                uint4 P0 = *hp(tok, u0);
                uint4 P1 = *hp(tok, u0 + 1);
                union { unsigned u[4]; bf16x8 b; } h_, l_;
                h_.u[0] = (P0.x >> 16) | (P0.y & 0xffff0000u);
                h_.u[1] = (P0.z >> 16) | (P0.w & 0xffff0000u);
                h_.u[2] = (P1.x >> 16) | (P1.y & 0xffff0000u);
                h_.u[3] = (P1.z >> 16) | (P1.w & 0xffff0000u);
                l_.u[0] = (P0.x & 0xffffu) | (P0.y << 16);
                l_.u[1] = (P0.z & 0xffffu) | (P0.w << 16);
                l_.u[2] = (P1.x & 0xffffu) | (P1.y << 16);
                l_.u[3] = (P1.z & 0xffffu) | (P1.w << 16);
                Bhi[ks] = h_.b;
                Blo[ks] = l_.b;
            }

            const float* bml = ebm + (e * 3 + l) * 128;
#pragma unroll
            for (int mt = 0; mt < 8; ++mt) {
                const float4 bb = *(const float4*)(bml + mt * 16 + g4 * 4);
                f32x4 acc;
                acc[0] = bb.x; acc[1] = bb.y; acc[2] = bb.z; acc[3] = bb.w;
#pragma unroll
                for (int ks = 0; ks < 4; ++ks) {
                    bf16x8 a = *(const bf16x8*)(wc + (((mt * 4 + ks) * 64 + lane) << 4));
                    acc = __builtin_amdgcn_mfma_f32_16x16x32_bf16(a, Bhi[ks], acc, 0, 0, 0);
                    acc = __builtin_amdgcn_mfma_f32_16x16x32_bf16(a, Blo[ks], acc, 0, 0, 0);
                }
                uint4 pk;
                pk.x = pack_hl(tanh_fast(acc[0]));
                pk.y = pack_hl(tanh_fast(acc[1]));
                pk.z = pack_hl(tanh_fast(acc[2]));
                pk.w = pack_hl(tanh_fast(acc[3]));
                *hp(tok, mt * 4 + g4) = pk;        // rows j = mt*16+g4*4..+3
            }
        }
        // ---- output dot: eo = h3 . ewo[e] + ebo[e]  (intra-wave) ----
        {
            float ps = 0.0f;
            const float* wo = ewo + e * 128;
#pragma unroll
            for (int c = 0; c < 8; ++c) {
                uint4 P = *hp(tok, g4 * 8 + c);
                const float4 wv = *(const float4*)(wo + g4 * 32 + c * 4);
                ps = fmaf(__uint_as_float(P.x & 0xffff0000u) + __uint_as_float(P.x << 16), wv.x, ps);
                ps = fmaf(__uint_as_float(P.y & 0xffff0000u) + __uint_as_float(P.y << 16), wv.y, ps);
                ps = fmaf(__uint_as_float(P.z & 0xffff0000u) + __uint_as_float(P.z << 16), wv.z, ps);
                ps = fmaf(__uint_as_float(P.w & 0xffff0000u) + __uint_as_float(P.w << 16), wv.w, ps);
            }
            ps += __shfl_xor(ps, 16, 64);
            ps += __shfl_xor(ps, 32, 64);
            float eo = ps + ebo[e];
            yacc = fmaf(gates_l[e * 128 + tok], eo, yacc);
        }
    }

    if (lane < 16) y[blk * T_BLK + tok] = yacc;
}

extern "C" void kernel_launch(void* const* d_in, const int* in_sizes, int n_in,
                              void* d_out, int out_size, void* d_ws, size_t ws_size,
                              hipStream_t stream) {
    const float* x   = (const float*)d_in[0];
    const float* ew1 = (const float*)d_in[1];
    const float* eb1 = (const float*)d_in[2];
    const float* ewm = (const float*)d_in[3];
    const float* ebm = (const float*)d_in[4];
    const float* ewo = (const float*)d_in[5];
    const float* ebo = (const float*)d_in[6];
    const float* gw1 = (const float*)d_in[7];
    const float* gb1 = (const float*)d_in[8];
    const float* gwm = (const float*)d_in[9];
    const float* gbm = (const float*)d_in[10];
    const float* gwo = (const float*)d_in[11];
    const float* gbo = (const float*)d_in[12];
    float* y = (float*)d_out;
    unsigned short* wsA = (unsigned short*)d_ws;   // 48*32KB = 1.5MB bf16 W frags

    // prep: pack expert mid-layer weights into MFMA fragment order
    pack_wm_kernel<<<384, 256, 0, stream>>>(ewm, wsA);

    hipFuncSetAttribute((const void*)moe_fused,
                        hipFuncAttributeMaxDynamicSharedMemorySize, SMEM_BYTES);
    moe_fused<<<dim3(N_TOK / T_BLK), dim3(THREADS), SMEM_BYTES, stream>>>(
        x, ew1, eb1, ewm, ebm, ewo, ebo, gw1, gb1, gwm, gbm, gwo, gbo, wsA, y);
}